// Round 1
// baseline (133.356 us; speedup 1.0000x reference)
//
#include <hip/hip_runtime.h>

#define NN 4096
#define DD 128
#define HH1 256

// workspace float offsets
#define WS_S    0        // 16384 : S = (weight*A)^2 / 128
#define WS_S2   16384    // 16384 : S^2
#define WS_S3   32768    // 16384 : S^3
#define WS_S4   49152    // 16384 : S^4
#define WS_W2S  65536    // 256   : row sums of W2
#define WS_B2S  65792    // 1     : sum of b2
#define WS_TACC 65808    // 10    : trace accumulators t2..t11 (zeroed by kA)
#define WS_DONE 65824    // 1     : done counter (uint, zeroed by kA)
#define WS_REGP 65840    // 8     : reg partials

__device__ __forceinline__ float waveReduce(float v) {
#pragma unroll
  for (int off = 32; off > 0; off >>= 1) v += __shfl_down(v, off, 64);
  return v;
}

// kA: S^2 (blocks 0..63), materialize S (64..71), w2s (72), b2s+zero (73),
//     reg partials (74..81)
__global__ __launch_bounds__(256) void kA(
    const float* __restrict__ weight, const float* __restrict__ Amat,
    const float* __restrict__ W2, const float* __restrict__ b2,
    float* __restrict__ ws) {
  const int b = blockIdx.x, tid = threadIdx.x;
  if (b < 64) {
    __shared__ float s_lds[DD * DD];  // full S, 64 KB
    const float4* w4 = (const float4*)weight;
    const float4* a4 = (const float4*)Amat;
    float4* s4 = (float4*)s_lds;
    const float inv = 1.0f / 128.0f;
    for (int e = tid; e < DD * DD / 4; e += 256) {
      float4 wv = w4[e], av = a4[e], o;
      float t;
      t = wv.x * av.x; o.x = t * t * inv;
      t = wv.y * av.y; o.y = t * t * inv;
      t = wv.z * av.z; o.z = t * t * inv;
      t = wv.w * av.w; o.w = t * t * inv;
      s4[e] = o;
    }
    __syncthreads();
    const int i = (b << 1) + (tid >> 7), j = tid & 127;
    const float* row = &s_lds[i * DD];  // broadcast reads
    float acc = 0.f;
#pragma unroll 8
    for (int k = 0; k < DD; ++k) acc = fmaf(row[k], s_lds[k * DD + j], acc);
    ws[WS_S2 + i * DD + j] = acc;
  } else if (b < 72) {
    const int base = (b - 64) * 2048;
    const float inv = 1.0f / 128.0f;
    for (int e = tid; e < 2048; e += 256) {
      const int idx = base + e;
      const float w = weight[idx] * Amat[idx];
      ws[WS_S + idx] = w * w * inv;
    }
  } else if (b == 72) {
    // w2s[j] = sum_k W2[j,k]; one thread per j
    const float4* r = (const float4*)(W2 + tid * 128);
    float4 s4 = make_float4(0.f, 0.f, 0.f, 0.f);
#pragma unroll 8
    for (int k = 0; k < 32; ++k) {
      const float4 v = r[k];
      s4.x += v.x; s4.y += v.y; s4.z += v.z; s4.w += v.w;
    }
    ws[WS_W2S + tid] = (s4.x + s4.y) + (s4.z + s4.w);
  } else if (b == 73) {
    __shared__ float red[4];
    float v = (tid < 128) ? b2[tid] : 0.f;
    v = waveReduce(v);
    if ((tid & 63) == 0) red[tid >> 6] = v;
    __syncthreads();
    if (tid == 0) ws[WS_B2S] = (red[0] + red[1]) + (red[2] + red[3]);
    if (tid >= 64 && tid < 74) ws[WS_TACC + (tid - 64)] = 0.f;
    if (tid == 96) *(unsigned int*)(ws + WS_DONE) = 0u;
  } else {
    const int bb = b - 74;
    const int base = bb * 2048;
    float s = 0.f;
    for (int e = tid; e < 2048; e += 256) {
      const int idx = base + e;
      s += fabsf(weight[idx] * Amat[idx]);
    }
    s = waveReduce(s);
    __shared__ float red[4];
    if ((tid & 63) == 0) red[tid >> 6] = s;
    __syncthreads();
    if (tid == 0) ws[WS_REGP + bb] = (red[0] + red[1]) + (red[2] + red[3]);
  }
}

// kB: blocks 0..127 compute S^3 = S^2*S and S^4 = S^2*S^2;
//     blocks 128.. compute f (fused y-dot + per-scalar MLP collapse)
__global__ __launch_bounds__(256) void kB(
    const float* __restrict__ x, const float* __restrict__ weight,
    const float* __restrict__ Amat, const float* __restrict__ bias,
    const float* __restrict__ W1, const float* __restrict__ b1v,
    float* __restrict__ ws, float* __restrict__ out) {
  const int tid = threadIdx.x;
  if (blockIdx.x < 128) {
    const int sb = blockIdx.x;
    const bool isS4 = sb >= 64;
    const int mb = isS4 ? sb - 64 : sb;
    const float* __restrict__ L = ws + WS_S2;
    const float* __restrict__ R = ws + (isS4 ? WS_S2 : WS_S);
    float* __restrict__ O = ws + (isS4 ? WS_S4 : WS_S3);
    const int i = (mb << 1) + (tid >> 7), j = tid & 127;
    float acc = 0.f;
#pragma unroll 8
    for (int k = 0; k < DD; ++k) acc = fmaf(L[i * DD + k], R[k * DD + j], acc);
    O[i * DD + j] = acc;
    return;
  }
  // ---- f block: 4 i (one per wave) x 64 n (one per lane) ----
  __shared__ float xs[64 * 132];    // x tile, padded stride 132 (bank-uniform)
  __shared__ float4 fq[4 * 256];    // per (i,j): {W1[i][j], b1[j], w2s[j], 0}
  __shared__ float wcol[4 * 128];   // W columns for the 4 i
  __shared__ float ts[64 * 5];      // output transpose staging
  const int fb = blockIdx.x - 128;
  const int i0 = (fb & 31) << 2, n0 = (fb >> 5) << 6;
  const float4* x4 = (const float4*)x;
  for (int e = tid; e < 64 * 32; e += 256) {
    const int r = e >> 5, c = e & 31;
    *(float4*)&xs[r * 132 + (c << 2)] = x4[(n0 + r) * 32 + c];
  }
  for (int e = tid; e < 512; e += 256) {
    const int w = e >> 7, k = e & 127;
    const int gi = k * DD + i0 + w;
    wcol[(w << 7) + k] = weight[gi] * Amat[gi];
  }
  const float* w2s = ws + WS_W2S;
  for (int e = tid; e < 1024; e += 256) {
    const int w = e >> 8, j = e & 255;
    fq[(w << 8) + j] = make_float4(W1[(i0 + w) * HH1 + j], b1v[j], w2s[j], 0.f);
  }
  __syncthreads();
  const int w = tid >> 6, l = tid & 63;
  // y[n,i] = x[n,:] . W[:,i] + bias[i]
  float t = bias[i0 + w];
  const float4* xr = (const float4*)&xs[l * 132];
  const float4* wc = (const float4*)&wcol[w << 7];
#pragma unroll
  for (int k = 0; k < 32; ++k) {
    const float4 xv = xr[k], wv = wc[k];
    t = fmaf(xv.x, wv.x, t);
    t = fmaf(xv.y, wv.y, t);
    t = fmaf(xv.z, wv.z, t);
    t = fmaf(xv.w, wv.w, t);
  }
  // f[n,i] = b2s + sum_j relu(t*W1[i,j] + b1[j]) * w2s[j]
  float acc = ws[WS_B2S];
  const float4* fp = &fq[w << 8];
#pragma unroll 8
  for (int j = 0; j < HH1; ++j) {
    const float4 c = fp[j];  // broadcast ds_read_b128
    acc = fmaf(fmaxf(fmaf(t, c.x, c.y), 0.f), c.z, acc);
  }
  ts[l * 5 + w] = acc;
  __syncthreads();
  if (tid < 64) {
    const float4 o = make_float4(ts[tid * 5 + 0], ts[tid * 5 + 1],
                                 ts[tid * 5 + 2], ts[tid * 5 + 3]);
    *(float4*)&out[(n0 + tid) * DD + i0] = o;
  }
}

// kC: fused S^7 dot + traces t2..t11, last-block assembles h_val and reg
__global__ __launch_bounds__(256) void kC(float* __restrict__ ws,
                                          float* __restrict__ out) {
  const int tid = threadIdx.x;
  const int i = (blockIdx.x << 1) + (tid >> 7), j = tid & 127;
  const float* S1 = ws + WS_S;
  const float* S2 = ws + WS_S2;
  const float* S3 = ws + WS_S3;
  const float* S4 = ws + WS_S4;
  const float a2 = S2[i * DD + j], a3 = S3[i * DD + j];
  const float a1 = S1[i * DD + j];
  const float b1t = S1[j * DD + i], b2t = S2[j * DD + i],
              b3t = S3[j * DD + i], b4t = S4[j * DD + i];
  float e7 = 0.f;  // S^7[i,j] = sum_k S3[i,k]*S4[k,j]
#pragma unroll 8
  for (int k = 0; k < DD; ++k) e7 = fmaf(S3[i * DD + k], S4[k * DD + j], e7);
  float c[10];
  c[0] = a1 * b1t;  // tr(S^2)
  c[1] = a2 * b1t;  // tr(S^3)
  c[2] = a2 * b2t;  // tr(S^4)
  c[3] = a3 * b2t;  // tr(S^5)
  c[4] = a3 * b3t;  // tr(S^6)
  c[5] = a3 * b4t;  // tr(S^7)
  c[6] = e7 * b1t;  // tr(S^8)
  c[7] = e7 * b2t;  // tr(S^9)
  c[8] = e7 * b3t;  // tr(S^10)
  c[9] = e7 * b4t;  // tr(S^11)
  __shared__ float red[4][10];
#pragma unroll
  for (int m = 0; m < 10; ++m) {
    const float v = waveReduce(c[m]);
    if ((tid & 63) == 0) red[tid >> 6][m] = v;
  }
  __syncthreads();
  if (tid == 0) {
    float* tacc = ws + WS_TACC;
    for (int m = 0; m < 10; ++m)
      atomicAdd(&tacc[m], (red[0][m] + red[1][m]) + (red[2][m] + red[3][m]));
    __threadfence();
    unsigned int* done = (unsigned int*)(ws + WS_DONE);
    const unsigned int old = atomicAdd(done, 1u);
    if (old == 63u) {
      __threadfence();
      // h_val = sum_{k=2..11} C(128,k) * tr(S^k)   (tr(S)=0: zero diagonal)
      double h = 0.0, C = 8128.0;  // C(128,2)
      for (int kk = 2; kk <= 11; ++kk) {
        const float tv = atomicAdd(&tacc[kk - 2], 0.0f);  // coherent read
        h += C * (double)tv;
        C = C * (double)(128 - kk) / (double)(kk + 1);
      }
      float reg = 0.f;
      for (int m = 0; m < 8; ++m) reg += ws[WS_REGP + m];
      out[NN * DD] = (float)h;
      out[NN * DD + 1] = reg;
    }
  }
}

extern "C" void kernel_launch(void* const* d_in, const int* in_sizes, int n_in,
                              void* d_out, int out_size, void* d_ws,
                              size_t ws_size, hipStream_t stream) {
  const float* x      = (const float*)d_in[0];
  const float* weight = (const float*)d_in[1];
  const float* bias   = (const float*)d_in[2];
  const float* Amat   = (const float*)d_in[3];
  const float* W1     = (const float*)d_in[4];
  const float* b1v    = (const float*)d_in[5];
  const float* W2     = (const float*)d_in[6];
  const float* b2     = (const float*)d_in[7];
  float* out = (float*)d_out;
  float* ws  = (float*)d_ws;

  kA<<<82, 256, 0, stream>>>(weight, Amat, W2, b2, ws);
  kB<<<128 + 2048, 256, 0, stream>>>(x, weight, Amat, bias, W1, b1v, ws, out);
  kC<<<64, 256, 0, stream>>>(ws, out);
}

// Round 2
// 107.241 us; speedup vs baseline: 1.2435x; 1.2435x over previous
//
#include <hip/hip_runtime.h>

#define NN 4096
#define DD 128
#define HH1 256

// ---------------- new-path workspace float offsets ----------------
#define WS_S    0        // 16384 : S = (weight*A)^2 / 128
#define WS_S2   16384    // 16384
#define WS_S3   32768    // 16384
#define WS_S4   49152    // 16384
#define WS_W    65536    // 16384 : W = weight*A
#define WS_W2S  81920    // 256
#define WS_PAIR 82176    // 512   : float2 {b1[j], w2s[j]}
#define WS_B2S  82688    // 1
#define WS_TACC 82696    // 10
#define WS_DONE 82708    // 1 (uint)
#define WS_REGP 82712    // 8
#define WS_XT   82944    // 524288 : xT[128][4096]
#define WS_YT   607232   // 524288 : yT[128][4096]
#define WS_REQ_FLOATS 1131520
#define WS_REQ_BYTES  (WS_REQ_FLOATS * 4UL)

// ---------------- old-path (fallback) offsets ----------------
#define O_S    0
#define O_S2   16384
#define O_S3   32768
#define O_S4   49152
#define O_W2S  65536
#define O_B2S  65792
#define O_TACC 65808
#define O_DONE 65824
#define O_REGP 65840

__device__ __forceinline__ float waveReduce(float v) {
#pragma unroll
  for (int off = 32; off > 0; off >>= 1) v += __shfl_down(v, off, 64);
  return v;
}

// =====================================================================
// NEW PATH
// =====================================================================

// kA2: 0..63 S^2 | 64..71 S & W | 72 w2s+pair | 73 b2s+zero | 74..81 reg
//      82..113 xT transpose
__global__ __launch_bounds__(256) void kA2(
    const float* __restrict__ weight, const float* __restrict__ Amat,
    const float* __restrict__ W2, const float* __restrict__ b2,
    const float* __restrict__ b1v, const float* __restrict__ x,
    float* __restrict__ ws) {
  const int b = blockIdx.x, tid = threadIdx.x;
  __shared__ float s_lds[DD * DD];   // 64 KB (S^2 blocks)
  __shared__ float xs[128 * 133];    // 68 KB (transpose blocks)
  if (b < 64) {
    const float4* w4 = (const float4*)weight;
    const float4* a4 = (const float4*)Amat;
    float4* s4 = (float4*)s_lds;
    const float inv = 1.0f / 128.0f;
    for (int e = tid; e < DD * DD / 4; e += 256) {
      float4 wv = w4[e], av = a4[e], o;
      float t;
      t = wv.x * av.x; o.x = t * t * inv;
      t = wv.y * av.y; o.y = t * t * inv;
      t = wv.z * av.z; o.z = t * t * inv;
      t = wv.w * av.w; o.w = t * t * inv;
      s4[e] = o;
    }
    __syncthreads();
    const int i = (b << 1) + (tid >> 7), j = tid & 127;
    const float* row = &s_lds[i * DD];
    float acc = 0.f;
#pragma unroll 8
    for (int k = 0; k < DD; ++k) acc = fmaf(row[k], s_lds[k * DD + j], acc);
    ws[WS_S2 + i * DD + j] = acc;
  } else if (b < 72) {
    const int base = (b - 64) * 2048;
    const float inv = 1.0f / 128.0f;
    for (int e = tid; e < 2048; e += 256) {
      const int idx = base + e;
      const float w = weight[idx] * Amat[idx];
      ws[WS_W + idx] = w;
      ws[WS_S + idx] = w * w * inv;
    }
  } else if (b == 72) {
    const float4* r = (const float4*)(W2 + tid * 128);
    float4 s4 = make_float4(0.f, 0.f, 0.f, 0.f);
#pragma unroll 8
    for (int k = 0; k < 32; ++k) {
      const float4 v = r[k];
      s4.x += v.x; s4.y += v.y; s4.z += v.z; s4.w += v.w;
    }
    const float w2sv = (s4.x + s4.y) + (s4.z + s4.w);
    ws[WS_W2S + tid] = w2sv;
    ((float2*)(ws + WS_PAIR))[tid] = make_float2(b1v[tid], w2sv);
  } else if (b == 73) {
    __shared__ float red[4];
    float v = (tid < 128) ? b2[tid] : 0.f;
    v = waveReduce(v);
    if ((tid & 63) == 0) red[tid >> 6] = v;
    __syncthreads();
    if (tid == 0) ws[WS_B2S] = (red[0] + red[1]) + (red[2] + red[3]);
    if (tid >= 64 && tid < 74) ws[WS_TACC + (tid - 64)] = 0.f;
    if (tid == 96) *(unsigned int*)(ws + WS_DONE) = 0u;
  } else if (b < 82) {
    const int bb = b - 74;
    const int base = bb * 2048;
    float s = 0.f;
    for (int e = tid; e < 2048; e += 256) {
      const int idx = base + e;
      s += fabsf(weight[idx] * Amat[idx]);
    }
    s = waveReduce(s);
    __shared__ float red2[4];
    if ((tid & 63) == 0) red2[tid >> 6] = s;
    __syncthreads();
    if (tid == 0) ws[WS_REGP + bb] = (red2[0] + red2[1]) + (red2[2] + red2[3]);
  } else {
    // xT transpose: 32 blocks, 128-row tiles
    const int n0 = (b - 82) * 128;
    const float4* x4 = (const float4*)x;
    for (int e = tid; e < 4096; e += 256) {
      const int r = e >> 5, c = e & 31;
      const float4 v = x4[(n0 + r) * 32 + c];
      float* p = &xs[r * 133 + (c << 2)];
      p[0] = v.x; p[1] = v.y; p[2] = v.z; p[3] = v.w;
    }
    __syncthreads();
    float* xT = ws + WS_XT;
    const int c = tid & 31, ks = tid >> 5;
#pragma unroll 4
    for (int m = 0; m < 16; ++m) {
      const int k = ks + (m << 3);
      float4 o;
      o.x = xs[((c << 2) + 0) * 133 + k];
      o.y = xs[((c << 2) + 1) * 133 + k];
      o.z = xs[((c << 2) + 2) * 133 + k];
      o.w = xs[((c << 2) + 3) * 133 + k];
      *(float4*)&xT[k * NN + n0 + (c << 2)] = o;
    }
  }
}

// kB2: 0..127 S^3/S^4 | 128..383 ky: yT[i][n] = x@W + bias (transposed)
__global__ __launch_bounds__(256) void kB2(const float* __restrict__ bias,
                                           float* __restrict__ ws) {
  const int tid = threadIdx.x;
  if (blockIdx.x < 128) {
    const int sb = blockIdx.x;
    const bool isS4 = sb >= 64;
    const int mb = isS4 ? sb - 64 : sb;
    const float* __restrict__ L = ws + WS_S2;
    const float* __restrict__ R = ws + (isS4 ? WS_S2 : WS_S);
    float* __restrict__ O = ws + (isS4 ? WS_S4 : WS_S3);
    const int i = (mb << 1) + (tid >> 7), j = tid & 127;
    float acc = 0.f;
#pragma unroll 8
    for (int k = 0; k < DD; ++k) acc = fmaf(L[i * DD + k], R[k * DD + j], acc);
    O[i * DD + j] = acc;
    return;
  }
  const int kb = blockIdx.x - 128;
  const int n0 = (kb & 15) << 8, i0 = (kb >> 4) << 3;  // 256 n x 8 i
  const int n = n0 + tid;
  const float* __restrict__ xT = ws + WS_XT;
  const float* __restrict__ Wm = ws + WS_W;
  float* __restrict__ yT = ws + WS_YT;
  float acc[8];
#pragma unroll
  for (int q = 0; q < 8; ++q) acc[q] = 0.f;
#pragma unroll 8
  for (int k = 0; k < DD; ++k) {
    const float xv = xT[k * NN + n];           // coalesced vector load
    const float* Wk = Wm + k * DD + i0;        // uniform -> s_load_dwordx8
#pragma unroll
    for (int q = 0; q < 8; ++q) acc[q] = fmaf(Wk[q], xv, acc[q]);
  }
#pragma unroll
  for (int q = 0; q < 8; ++q) yT[(i0 + q) * NN + n] = acc[q] + bias[i0 + q];
}

// kC2: 0..511 kf (MLP collapse from yT) | 512..575 traces + final
__global__ __launch_bounds__(256) void kC2(const float* __restrict__ W1,
                                           float* __restrict__ ws,
                                           float* __restrict__ out) {
  const int tid = threadIdx.x;
  if (blockIdx.x < 512) {
    __shared__ float ts[256 * 5];
    const int fb = blockIdx.x;
    const int n0 = (fb >> 5) << 8, i0 = (fb & 31) << 2;  // 256 n x 4 i
    const int w = tid >> 6, l = tid & 63;
    const int iu = __builtin_amdgcn_readfirstlane(i0 + w);  // force SGPR
    const float* __restrict__ yT = ws + WS_YT;
    float t[4];
#pragma unroll
    for (int q = 0; q < 4; ++q) t[q] = yT[iu * NN + n0 + (q << 6) + l];
    const float sb2 = ws[WS_B2S];
    float acc[4];
#pragma unroll
    for (int q = 0; q < 4; ++q) acc[q] = sb2;
    const float* __restrict__ W1row = W1 + iu * HH1;  // uniform -> s_load
    const float2* __restrict__ pr = (const float2*)(ws + WS_PAIR);
#pragma unroll 8
    for (int j = 0; j < HH1; ++j) {
      const float sw1 = W1row[j];      // s_load
      const float2 p = pr[j];          // s_load_dwordx2
      const float vb = p.x;            // one v_mov, amortized over 4 n
#pragma unroll
      for (int q = 0; q < 4; ++q) {
        const float h = fmaxf(fmaf(t[q], sw1, vb), 0.f);
        acc[q] = fmaf(h, p.y, acc[q]);
      }
    }
#pragma unroll
    for (int q = 0; q < 4; ++q) ts[((q << 6) + l) * 5 + w] = acc[q];
    __syncthreads();
    const int m = tid;  // 256 rows
    float4 o;
    o.x = ts[m * 5 + 0]; o.y = ts[m * 5 + 1];
    o.z = ts[m * 5 + 2]; o.w = ts[m * 5 + 3];
    *(float4*)&out[(n0 + m) * DD + i0] = o;
    return;
  }
  // ---- trace blocks ----
  const int tb = blockIdx.x - 512;
  const int i = (tb << 1) + (tid >> 7), j = tid & 127;
  const float* S1 = ws + WS_S;
  const float* S2 = ws + WS_S2;
  const float* S3 = ws + WS_S3;
  const float* S4 = ws + WS_S4;
  const float a1 = S1[i * DD + j], a2 = S2[i * DD + j], a3 = S3[i * DD + j];
  const float b1t = S1[j * DD + i], b2t = S2[j * DD + i],
              b3t = S3[j * DD + i], b4t = S4[j * DD + i];
  float e7 = 0.f;
#pragma unroll 8
  for (int k = 0; k < DD; ++k) e7 = fmaf(S3[i * DD + k], S4[k * DD + j], e7);
  float c[10];
  c[0] = a1 * b1t; c[1] = a2 * b1t; c[2] = a2 * b2t; c[3] = a3 * b2t;
  c[4] = a3 * b3t; c[5] = a3 * b4t; c[6] = e7 * b1t; c[7] = e7 * b2t;
  c[8] = e7 * b3t; c[9] = e7 * b4t;
  __shared__ float red[4][10];
#pragma unroll
  for (int m = 0; m < 10; ++m) {
    const float v = waveReduce(c[m]);
    if ((tid & 63) == 0) red[tid >> 6][m] = v;
  }
  __syncthreads();
  if (tid == 0) {
    float* tacc = ws + WS_TACC;
    for (int m = 0; m < 10; ++m)
      atomicAdd(&tacc[m], (red[0][m] + red[1][m]) + (red[2][m] + red[3][m]));
    __threadfence();
    unsigned int* done = (unsigned int*)(ws + WS_DONE);
    const unsigned int old = atomicAdd(done, 1u);
    if (old == 63u) {
      __threadfence();
      double h = 0.0, C = 8128.0;  // C(128,2)
      for (int kk = 2; kk <= 11; ++kk) {
        const float tv = atomicAdd(&tacc[kk - 2], 0.0f);
        h += C * (double)tv;
        C = C * (double)(128 - kk) / (double)(kk + 1);
      }
      float reg = 0.f;
      for (int m = 0; m < 8; ++m) reg += ws[WS_REGP + m];
      out[NN * DD] = (float)h;
      out[NN * DD + 1] = reg;
    }
  }
}

// =====================================================================
// OLD PATH (round-1, fallback when ws_size is too small)
// =====================================================================
__global__ __launch_bounds__(256) void kA_old(
    const float* __restrict__ weight, const float* __restrict__ Amat,
    const float* __restrict__ W2, const float* __restrict__ b2,
    float* __restrict__ ws) {
  const int b = blockIdx.x, tid = threadIdx.x;
  if (b < 64) {
    __shared__ float s_lds[DD * DD];
    const float4* w4 = (const float4*)weight;
    const float4* a4 = (const float4*)Amat;
    float4* s4 = (float4*)s_lds;
    const float inv = 1.0f / 128.0f;
    for (int e = tid; e < DD * DD / 4; e += 256) {
      float4 wv = w4[e], av = a4[e], o;
      float t;
      t = wv.x * av.x; o.x = t * t * inv;
      t = wv.y * av.y; o.y = t * t * inv;
      t = wv.z * av.z; o.z = t * t * inv;
      t = wv.w * av.w; o.w = t * t * inv;
      s4[e] = o;
    }
    __syncthreads();
    const int i = (b << 1) + (tid >> 7), j = tid & 127;
    const float* row = &s_lds[i * DD];
    float acc = 0.f;
#pragma unroll 8
    for (int k = 0; k < DD; ++k) acc = fmaf(row[k], s_lds[k * DD + j], acc);
    ws[O_S2 + i * DD + j] = acc;
  } else if (b < 72) {
    const int base = (b - 64) * 2048;
    const float inv = 1.0f / 128.0f;
    for (int e = tid; e < 2048; e += 256) {
      const int idx = base + e;
      const float w = weight[idx] * Amat[idx];
      ws[O_S + idx] = w * w * inv;
    }
  } else if (b == 72) {
    const float4* r = (const float4*)(W2 + tid * 128);
    float4 s4 = make_float4(0.f, 0.f, 0.f, 0.f);
#pragma unroll 8
    for (int k = 0; k < 32; ++k) {
      const float4 v = r[k];
      s4.x += v.x; s4.y += v.y; s4.z += v.z; s4.w += v.w;
    }
    ws[O_W2S + tid] = (s4.x + s4.y) + (s4.z + s4.w);
  } else if (b == 73) {
    __shared__ float red[4];
    float v = (tid < 128) ? b2[tid] : 0.f;
    v = waveReduce(v);
    if ((tid & 63) == 0) red[tid >> 6] = v;
    __syncthreads();
    if (tid == 0) ws[O_B2S] = (red[0] + red[1]) + (red[2] + red[3]);
    if (tid >= 64 && tid < 74) ws[O_TACC + (tid - 64)] = 0.f;
    if (tid == 96) *(unsigned int*)(ws + O_DONE) = 0u;
  } else {
    const int bb = b - 74;
    const int base = bb * 2048;
    float s = 0.f;
    for (int e = tid; e < 2048; e += 256) {
      const int idx = base + e;
      s += fabsf(weight[idx] * Amat[idx]);
    }
    s = waveReduce(s);
    __shared__ float red[4];
    if ((tid & 63) == 0) red[tid >> 6] = s;
    __syncthreads();
    if (tid == 0) ws[O_REGP + bb] = (red[0] + red[1]) + (red[2] + red[3]);
  }
}

__global__ __launch_bounds__(256) void kB_old(
    const float* __restrict__ x, const float* __restrict__ weight,
    const float* __restrict__ Amat, const float* __restrict__ bias,
    const float* __restrict__ W1, const float* __restrict__ b1v,
    float* __restrict__ ws, float* __restrict__ out) {
  const int tid = threadIdx.x;
  if (blockIdx.x < 128) {
    const int sb = blockIdx.x;
    const bool isS4 = sb >= 64;
    const int mb = isS4 ? sb - 64 : sb;
    const float* __restrict__ L = ws + O_S2;
    const float* __restrict__ R = ws + (isS4 ? O_S2 : O_S);
    float* __restrict__ O = ws + (isS4 ? O_S4 : O_S3);
    const int i = (mb << 1) + (tid >> 7), j = tid & 127;
    float acc = 0.f;
#pragma unroll 8
    for (int k = 0; k < DD; ++k) acc = fmaf(L[i * DD + k], R[k * DD + j], acc);
    O[i * DD + j] = acc;
    return;
  }
  __shared__ float xs[64 * 132];
  __shared__ float4 fq[4 * 256];
  __shared__ float wcol[4 * 128];
  __shared__ float ts[64 * 5];
  const int fb = blockIdx.x - 128;
  const int i0 = (fb & 31) << 2, n0 = (fb >> 5) << 6;
  const float4* x4 = (const float4*)x;
  for (int e = tid; e < 64 * 32; e += 256) {
    const int r = e >> 5, c = e & 31;
    *(float4*)&xs[r * 132 + (c << 2)] = x4[(n0 + r) * 32 + c];
  }
  for (int e = tid; e < 512; e += 256) {
    const int w = e >> 7, k = e & 127;
    const int gi = k * DD + i0 + w;
    wcol[(w << 7) + k] = weight[gi] * Amat[gi];
  }
  const float* w2s = ws + O_W2S;
  for (int e = tid; e < 1024; e += 256) {
    const int w = e >> 8, j = e & 255;
    fq[(w << 8) + j] = make_float4(W1[(i0 + w) * HH1 + j], b1v[j], w2s[j], 0.f);
  }
  __syncthreads();
  const int w = tid >> 6, l = tid & 63;
  float t = bias[i0 + w];
  const float4* xr = (const float4*)&xs[l * 132];
  const float4* wc = (const float4*)&wcol[w << 7];
#pragma unroll
  for (int k = 0; k < 32; ++k) {
    const float4 xv = xr[k], wv = wc[k];
    t = fmaf(xv.x, wv.x, t);
    t = fmaf(xv.y, wv.y, t);
    t = fmaf(xv.z, wv.z, t);
    t = fmaf(xv.w, wv.w, t);
  }
  float acc = ws[O_B2S];
  const float4* fp = &fq[w << 8];
#pragma unroll 8
  for (int j = 0; j < HH1; ++j) {
    const float4 c = fp[j];
    acc = fmaf(fmaxf(fmaf(t, c.x, c.y), 0.f), c.z, acc);
  }
  ts[l * 5 + w] = acc;
  __syncthreads();
  if (tid < 64) {
    const float4 o = make_float4(ts[tid * 5 + 0], ts[tid * 5 + 1],
                                 ts[tid * 5 + 2], ts[tid * 5 + 3]);
    *(float4*)&out[(n0 + tid) * DD + i0] = o;
  }
}

__global__ __launch_bounds__(256) void kC_old(float* __restrict__ ws,
                                              float* __restrict__ out) {
  const int tid = threadIdx.x;
  const int i = (blockIdx.x << 1) + (tid >> 7), j = tid & 127;
  const float* S1 = ws + O_S;
  const float* S2 = ws + O_S2;
  const float* S3 = ws + O_S3;
  const float* S4 = ws + O_S4;
  const float a1 = S1[i * DD + j], a2 = S2[i * DD + j], a3 = S3[i * DD + j];
  const float b1t = S1[j * DD + i], b2t = S2[j * DD + i],
              b3t = S3[j * DD + i], b4t = S4[j * DD + i];
  float e7 = 0.f;
#pragma unroll 8
  for (int k = 0; k < DD; ++k) e7 = fmaf(S3[i * DD + k], S4[k * DD + j], e7);
  float c[10];
  c[0] = a1 * b1t; c[1] = a2 * b1t; c[2] = a2 * b2t; c[3] = a3 * b2t;
  c[4] = a3 * b3t; c[5] = a3 * b4t; c[6] = e7 * b1t; c[7] = e7 * b2t;
  c[8] = e7 * b3t; c[9] = e7 * b4t;
  __shared__ float red[4][10];
#pragma unroll
  for (int m = 0; m < 10; ++m) {
    const float v = waveReduce(c[m]);
    if ((tid & 63) == 0) red[tid >> 6][m] = v;
  }
  __syncthreads();
  if (tid == 0) {
    float* tacc = ws + O_TACC;
    for (int m = 0; m < 10; ++m)
      atomicAdd(&tacc[m], (red[0][m] + red[1][m]) + (red[2][m] + red[3][m]));
    __threadfence();
    unsigned int* done = (unsigned int*)(ws + O_DONE);
    const unsigned int old = atomicAdd(done, 1u);
    if (old == 63u) {
      __threadfence();
      double h = 0.0, C = 8128.0;
      for (int kk = 2; kk <= 11; ++kk) {
        const float tv = atomicAdd(&tacc[kk - 2], 0.0f);
        h += C * (double)tv;
        C = C * (double)(128 - kk) / (double)(kk + 1);
      }
      float reg = 0.f;
      for (int m = 0; m < 8; ++m) reg += ws[O_REGP + m];
      out[NN * DD] = (float)h;
      out[NN * DD + 1] = reg;
    }
  }
}

extern "C" void kernel_launch(void* const* d_in, const int* in_sizes, int n_in,
                              void* d_out, int out_size, void* d_ws,
                              size_t ws_size, hipStream_t stream) {
  const float* x      = (const float*)d_in[0];
  const float* weight = (const float*)d_in[1];
  const float* bias   = (const float*)d_in[2];
  const float* Amat   = (const float*)d_in[3];
  const float* W1     = (const float*)d_in[4];
  const float* b1v    = (const float*)d_in[5];
  const float* W2     = (const float*)d_in[6];
  const float* b2     = (const float*)d_in[7];
  float* out = (float*)d_out;
  float* ws  = (float*)d_ws;

  if (ws_size >= WS_REQ_BYTES) {
    kA2<<<114, 256, 0, stream>>>(weight, Amat, W2, b2, b1v, x, ws);
    kB2<<<384, 256, 0, stream>>>(bias, ws);
    kC2<<<576, 256, 0, stream>>>(W1, ws, out);
  } else {
    kA_old<<<82, 256, 0, stream>>>(weight, Amat, W2, b2, ws);
    kB_old<<<128 + 2048, 256, 0, stream>>>(x, weight, Amat, bias, W1, b1v, ws,
                                           out);
    kC_old<<<64, 256, 0, stream>>>(ws, out);
  }
}